// Round 5
// baseline (320.556 us; speedup 1.0000x reference)
//
#include <hip/hip_runtime.h>
#include <hip/hip_fp16.h>
#include <math.h>

#define BB   4
#define C_   128
#define H_   96
#define W_   192
#define COUT 128
#define DG_  2
#define CG_  64
#define K_   9
#define HO   96
#define WO   192
#define HW   (H_ * W_)       // 18432
#define OMCH 54
#define RDIM (C_ * K_)       // 1152
#define NKS  (RDIM / 32)     // 36 K-steps
#define WTROW 2304           // ushorts per W row: 36 steps * 64

typedef __attribute__((ext_vector_type(8))) short bf16x8;
typedef __attribute__((ext_vector_type(4))) float f32x4;

static __device__ __forceinline__ ushort f2bf(float f) {
  union { float f; uint u; } v; v.f = f;
  uint r = v.u + 0x7fff + ((v.u >> 16) & 1);   // RNE
  return (ushort)(r >> 16);
}

// ---------------------------------------------------------------------------
// Prep:
//  Wt2[o][step][koct][16]: hi8 || lo8 bf16 split of w_deform, r = g*576+k*64+cg
//  Awo[64][1152]: offset-conv A, r'' = k*128+c, rows o'=g*32+j (j<27, else 0)
// ---------------------------------------------------------------------------
__global__ __launch_bounds__(256) void prep_k(
    const float* __restrict__ wd, const float* __restrict__ wo,
    ushort* __restrict__ Wt2, ushort* __restrict__ Awo) {
  int i = blockIdx.x * 256 + threadIdx.x;
  if (i < 128 * RDIM) {
    int o = i / RDIM, r = i - o * RDIM;
    int g = r / 576, t = r - g * 576;
    int k = t >> 6, cg = t & 63;
    float w = wd[((size_t)o * C_ + g * 64 + cg) * 9 + k];
    ushort hi = f2bf(w);
    union { float f; uint u; } hv; hv.u = (uint)hi << 16;
    ushort lo = f2bf(w - hv.f);
    int step = r >> 5, within = r & 31;
    int koct = within >> 3, j = within & 7;
    size_t base = (size_t)o * WTROW + step * 64 + koct * 16 + j;
    Wt2[base] = hi;
    Wt2[base + 8] = lo;
  }
  if (i < 64 * RDIM) {
    int o2 = i / RDIM, r = i - o2 * RDIM;
    int k = r >> 7, c = r & 127;
    int g = o2 >> 5, j = o2 & 31;
    float v = (((c >> 6) == g) && (j < 27))
                ? wo[(((size_t)(g * 27 + j)) * 64 + (c & 63)) * 9 + k] : 0.f;
    Awo[i] = f2bf(v);
  }
}

// ---------------------------------------------------------------------------
// Offset conv as MFMA (R3 exact — proven).
// ---------------------------------------------------------------------------
__global__ __launch_bounds__(256) void offset_mfma_k(
    const float* __restrict__ x, const ushort* __restrict__ Awo,
    const float* __restrict__ b_offset, float* __restrict__ om) {
  __shared__ uint s_val[2][64][20];

  int bid = blockIdx.x;
  int blk = (bid & 7) * 144 + (bid >> 3);
  int wt = blk % 3, bh = blk / 3;
  int ho = bh % HO, b = bh / HO;
  int wo0 = wt * 64;
  int lane = threadIdx.x & 63, wv = threadIdx.x >> 6;

  const float* xb = x + (size_t)b * C_ * HW;
  f32x4 acc[4];
#pragma unroll
  for (int n = 0; n < 4; ++n) acc[n] = (f32x4){0.f, 0.f, 0.f, 0.f};

  const ushort* abase = Awo + (size_t)(wv * 16 + (lane & 15)) * RDIM + (lane >> 4) * 8;

  float gv[8];

  auto patch_gather = [&](int step) {
    int k = step >> 2;
    int dy = k / 3, dx = k - dy * 3;
    int y  = ho - 2 + 2 * dy;
    int xc = wo0 + lane - 2 + 2 * dx;
    bool ok = (y >= 0) & (y < H_) & (xc >= 0) & (xc < W_);
    int c0 = (step & 3) * 32 + wv * 8;
    const float* pl = xb + ((ptrdiff_t)c0 * HW + y * W_ + xc);
#pragma unroll
    for (int j = 0; j < 8; ++j) { gv[j] = ok ? *pl : 0.f; pl += HW; }
  };

  auto patch_finish = [&](int nb) {
    uint res[4];
#pragma unroll
    for (int j = 0; j < 8; ++j) {
      uint bf = (uint)f2bf(gv[j]);
      if (j & 1) res[j >> 1] |= bf << 16; else res[j >> 1] = bf;
    }
    *(int4*)&s_val[nb][lane][wv * 4] = *(int4*)&res[0];
  };

  auto mfma_step = [&](int step, int cb) {
    bf16x8 af = *(const bf16x8*)(abase + step * 32);
#pragma unroll
    for (int n = 0; n < 4; ++n) {
      bf16x8 bfr = *(const bf16x8*)&s_val[cb][n * 16 + (lane & 15)][(lane >> 4) * 4];
      acc[n] = __builtin_amdgcn_mfma_f32_16x16x32_bf16(af, bfr, acc[n], 0, 0, 0);
    }
  };

  patch_gather(0);
  patch_finish(0);
  __syncthreads();
  for (int it = 0; it < NKS - 1; ++it) {
    patch_gather(it + 1);
    mfma_step(it, it & 1);
    patch_finish((it + 1) & 1);
    __syncthreads();
  }
  mfma_step(NKS - 1, (NKS - 1) & 1);

  int col = lane & 15, rgrp = lane >> 4;
#pragma unroll
  for (int n = 0; n < 4; ++n)
#pragma unroll
    for (int ri = 0; ri < 4; ++ri) {
      int o2 = wv * 16 + rgrp * 4 + ri;
      int g = o2 >> 5, j = o2 & 31;
      if (j < 27) {
        int ch = g * 27 + j;
        om[((size_t)(b * OMCH + ch) * HO + ho) * WO + wo0 + n * 16 + col] =
            acc[n][ri] + b_offset[ch];
      }
    }
}

// ---------------------------------------------------------------------------
// Main kernel: R3 structure (64 px x 128 Cout, 1152 blocks) + depth-2 gather
// pipeline (2 register sets, triple-buffered val LDS, 1 barrier/step) +
// split-bf16 W (hi/lo) compensation.
// ---------------------------------------------------------------------------
#define VAL_GATHER(step, G00, G01, G10, G11, WG) do {                         \
    int g_ = (step) >= 18;                                                    \
    int ks_ = (step) - g_ * 18;                                               \
    int k_ = ks_ >> 1, half_ = ks_ & 1;                                       \
    int ci_ = (g_ * 9 + k_) * 64 + lane;                                      \
    uint aw_ = s_addr[ci_];                                                   \
    uint2 wp_ = s_w[ci_];                                                     \
    union { __half2 h; uint u; } ua_, ub_;                                    \
    ua_.u = wp_.x; ub_.u = wp_.y;                                             \
    float2 w01_ = __half22float2(ua_.h);                                      \
    float2 w23_ = __half22float2(ub_.h);                                      \
    WG = make_float4(w01_.x, w01_.y, w23_.x, w23_.y);                         \
    int a0_  = (int)(aw_ & 0x7fffu);                                          \
    int dx_  = (int)((aw_ >> 15) & 1u);                                       \
    int dyw_ = (int)((aw_ >> 16) & 1u) * W_;                                  \
    const float* pl_ = xb + (size_t)(g_ * 64 + half_ * 32 + wv * 8) * HW;     \
    _Pragma("unroll")                                                         \
    for (int j_ = 0; j_ < 8; ++j_) {                                          \
      G00[j_] = pl_[a0_];                                                     \
      G01[j_] = pl_[a0_ + dx_];                                               \
      G10[j_] = pl_[a0_ + dyw_];                                              \
      G11[j_] = pl_[a0_ + dyw_ + dx_];                                        \
      pl_ += HW;                                                              \
    }                                                                         \
  } while (0)

#define VAL_FINISH(G00, G01, G10, G11, WG, nb) do {                           \
    uint res_[4];                                                             \
    _Pragma("unroll")                                                         \
    for (int j_ = 0; j_ < 8; ++j_) {                                          \
      float v_ = WG.x * G00[j_] + WG.y * G01[j_] +                            \
                 WG.z * G10[j_] + WG.w * G11[j_];                             \
      uint bf_ = (uint)f2bf(v_);                                              \
      if (j_ & 1) res_[j_ >> 1] |= bf_ << 16; else res_[j_ >> 1] = bf_;       \
    }                                                                         \
    *(int4*)&s_val[nb][lane][wv * 4] = *(int4*)&res_[0];                      \
  } while (0)

__global__ __launch_bounds__(256) void deform_main_k(
    const float* __restrict__ x, const float* __restrict__ om,
    const ushort* __restrict__ Wt2, float* __restrict__ out) {
  __shared__ uint  s_addr[18 * 64];        // 4608 B: a0|dx<<15|dy<<16
  __shared__ uint2 s_w[18 * 64];           // 9216 B: 4 x f16 mask-folded weights
  __shared__ uint  s_val[3][64][20];       // 15360 B (triple buffer)

  int bid = blockIdx.x;
  int blk = (bid & 7) * 144 + (bid >> 3);
  int wt = blk % 3, bh = blk / 3;
  int ho = bh % HO, b = bh / HO;
  int wo0 = wt * 64;
  int tid = threadIdx.x;
  int lane = tid & 63, wv = tid >> 6;

  // ---- phase 0: bilinear coefficients (R3 exact) ----
  for (int e = tid; e < 18 * 64; e += 256) {
    int p = e & 63, gk = e >> 6;
    int g = gk / 9, k = gk - g * 9;
    int wo = wo0 + p;
    const float* omb = om + (size_t)b * OMCH * HW + (size_t)ho * WO + wo;
    float offy = omb[(size_t)(g * 18 + k * 2 + 0) * HW];
    float offx = omb[(size_t)(g * 18 + k * 2 + 1) * HW];
    float z    = omb[(size_t)(36 + g * 9 + k) * HW];
    float msk  = 2.f / (1.f + __expf(-z));
    float py = (float)(ho - 2 + (k / 3) * 2) + offy;
    float px = (float)(wo - 2 + (k % 3) * 2) + offx;
    float y0f = floorf(py), x0f = floorf(px);
    int   y0 = (int)y0f, x0 = (int)x0f;
    float ty = py - y0f, tx = px - x0f;
    float wy0 = (y0 >= 0 && y0 < H_)       ? (1.f - ty) : 0.f;
    float wy1 = (y0 >= -1 && y0 < H_ - 1)  ? ty         : 0.f;
    float wx0 = (x0 >= 0 && x0 < W_)       ? (1.f - tx) : 0.f;
    float wx1 = (x0 >= -1 && x0 < W_ - 1)  ? tx         : 0.f;
    int y0c = min(max(y0, 0), H_ - 1), y1c = min(max(y0 + 1, 0), H_ - 1);
    int x0c = min(max(x0, 0), W_ - 1), x1c = min(max(x0 + 1, 0), W_ - 1);
    s_addr[e] = (uint)(y0c * W_ + x0c) | ((uint)(x1c - x0c) << 15)
              | ((uint)(y1c - y0c) << 16);
    union { __half2 h; uint u; } u01, u23;
    u01.h = __half2{__float2half(wy0 * wx0 * msk), __float2half(wy0 * wx1 * msk)};
    u23.h = __half2{__float2half(wy1 * wx0 * msk), __float2half(wy1 * wx1 * msk)};
    s_w[e] = make_uint2(u01.u, u23.u);
  }

  const float* xb = x + (size_t)b * C_ * HW;

  f32x4 acc[2][4];
#pragma unroll
  for (int m = 0; m < 2; ++m)
#pragma unroll
    for (int n = 0; n < 4; ++n) acc[m][n] = (f32x4){0.f, 0.f, 0.f, 0.f};

  const ushort* wrow0 = Wt2 + (size_t)(wv * 32 + (lane & 15)) * WTROW + (lane >> 4) * 16;
  const ushort* wrow1 = wrow0 + (size_t)16 * WTROW;

  float A00[8], A01[8], A10[8], A11[8]; float4 wgA;
  float B00[8], B01[8], B10[8], B11[8]; float4 wgB;

  auto mfma_step = [&](int cb, bf16x8 h0, bf16x8 l0, bf16x8 h1, bf16x8 l1) {
#pragma unroll
    for (int n = 0; n < 4; ++n) {
      bf16x8 bfr = *(const bf16x8*)&s_val[cb][n * 16 + (lane & 15)][(lane >> 4) * 4];
      acc[0][n] = __builtin_amdgcn_mfma_f32_16x16x32_bf16(h0, bfr, acc[0][n], 0, 0, 0);
      acc[0][n] = __builtin_amdgcn_mfma_f32_16x16x32_bf16(l0, bfr, acc[0][n], 0, 0, 0);
      acc[1][n] = __builtin_amdgcn_mfma_f32_16x16x32_bf16(h1, bfr, acc[1][n], 0, 0, 0);
      acc[1][n] = __builtin_amdgcn_mfma_f32_16x16x32_bf16(l1, bfr, acc[1][n], 0, 0, 0);
    }
  };

  __syncthreads();                 // coeffs ready
  VAL_GATHER(0, A00, A01, A10, A11, wgA);
  VAL_FINISH(A00, A01, A10, A11, wgA, 0);
  VAL_GATHER(1, B00, B01, B10, B11, wgB);
  bf16x8 c_h0 = *(const bf16x8*)(wrow0);
  bf16x8 c_l0 = *(const bf16x8*)(wrow0 + 8);
  bf16x8 c_h1 = *(const bf16x8*)(wrow1);
  bf16x8 c_l1 = *(const bf16x8*)(wrow1 + 8);
  __syncthreads();                 // buf0 visible

  for (int it2 = 0; it2 < NKS; it2 += 2) {
    {   // ---- even body: gather(it+2) -> A-set, finish B-set ----
      int it = it2;
      if (it + 2 < NKS) VAL_GATHER(it + 2, A00, A01, A10, A11, wgA);
      bf16x8 n_h0 = c_h0, n_l0 = c_l0, n_h1 = c_h1, n_l1 = c_l1;
      if (it + 1 < NKS) {
        n_h0 = *(const bf16x8*)(wrow0 + (it + 1) * 64);
        n_l0 = *(const bf16x8*)(wrow0 + (it + 1) * 64 + 8);
        n_h1 = *(const bf16x8*)(wrow1 + (it + 1) * 64);
        n_l1 = *(const bf16x8*)(wrow1 + (it + 1) * 64 + 8);
      }
      mfma_step(it % 3, c_h0, c_l0, c_h1, c_l1);
      if (it + 1 < NKS) VAL_FINISH(B00, B01, B10, B11, wgB, (it + 1) % 3);
      __syncthreads();
      c_h0 = n_h0; c_l0 = n_l0; c_h1 = n_h1; c_l1 = n_l1;
    }
    {   // ---- odd body: gather(it+2) -> B-set, finish A-set ----
      int it = it2 + 1;
      if (it + 2 < NKS) VAL_GATHER(it + 2, B00, B01, B10, B11, wgB);
      bf16x8 n_h0 = c_h0, n_l0 = c_l0, n_h1 = c_h1, n_l1 = c_l1;
      if (it + 1 < NKS) {
        n_h0 = *(const bf16x8*)(wrow0 + (it + 1) * 64);
        n_l0 = *(const bf16x8*)(wrow0 + (it + 1) * 64 + 8);
        n_h1 = *(const bf16x8*)(wrow1 + (it + 1) * 64);
        n_l1 = *(const bf16x8*)(wrow1 + (it + 1) * 64 + 8);
      }
      mfma_step(it % 3, c_h0, c_l0, c_h1, c_l1);
      if (it + 1 < NKS) VAL_FINISH(A00, A01, A10, A11, wgA, (it + 1) % 3);
      __syncthreads();
      c_h0 = n_h0; c_l0 = n_l0; c_h1 = n_h1; c_l1 = n_l1;
    }
  }

  // ---- epilogue: C/D layout col=lane&15, row=(lane>>4)*4+reg ----
  int col = lane & 15, rgrp = lane >> 4;
#pragma unroll
  for (int m = 0; m < 2; ++m)
#pragma unroll
    for (int n = 0; n < 4; ++n)
#pragma unroll
      for (int ri = 0; ri < 4; ++ri) {
        int o = wv * 32 + m * 16 + rgrp * 4 + ri;
        out[((size_t)(b * COUT + o) * HO + ho) * WO + wo0 + n * 16 + col] = acc[m][n][ri];
      }
}

// ---------------------------------------------------------------------------
extern "C" void kernel_launch(void* const* d_in, const int* in_sizes, int n_in,
                              void* d_out, int out_size, void* d_ws, size_t ws_size,
                              hipStream_t stream) {
  const float* x        = (const float*)d_in[0];
  const float* w_offset = (const float*)d_in[1];
  const float* b_offset = (const float*)d_in[2];
  const float* w_deform = (const float*)d_in[3];
  float* out = (float*)d_out;

  char* ws = (char*)d_ws;
  float*  om  = (float*)ws;                            // 15,925,248 B
  ushort* Wt2 = (ushort*)(ws + 15925248);              //    589,824 B
  ushort* Awo = (ushort*)(ws + 15925248 + 589824);     //    147,456 B

  prep_k<<<576, 256, 0, stream>>>(w_deform, w_offset, Wt2, Awo);
  offset_mfma_k<<<1152, 256, 0, stream>>>(x, Awo, b_offset, om);
  deform_main_k<<<1152, 256, 0, stream>>>(x, om, Wt2, out);
}

// Round 6
// 259.339 us; speedup vs baseline: 1.2361x; 1.2361x over previous
//
#include <hip/hip_runtime.h>
#include <hip/hip_fp16.h>
#include <math.h>

#define BB   4
#define C_   128
#define H_   96
#define W_   192
#define COUT 128
#define DG_  2
#define CG_  64
#define K_   9
#define HO   96
#define WO   192
#define HW   (H_ * W_)       // 18432
#define OMCH 54
#define RDIM (C_ * K_)       // 1152
#define NKS  (RDIM / 32)     // 36 K-steps

typedef __attribute__((ext_vector_type(8))) short bf16x8;
typedef __attribute__((ext_vector_type(4))) float f32x4;

// 8-byte pair with only 4-byte alignment guarantee (legal for any dword addr)
struct __attribute__((packed, aligned(4))) fpair { float x, y; };

static __device__ __forceinline__ ushort f2bf(float f) {
  union { float f; uint u; } v; v.f = f;
  uint r = v.u + 0x7fff + ((v.u >> 16) & 1);   // RNE
  return (ushort)(r >> 16);
}

// ---------------------------------------------------------------------------
// Prep (R3 version): bf16 weights in k-major r-orderings.
//  Wt [128][1152]  r' = g*576 + k*64 + cg   (main GEMM A)
//  Awo[ 64][1152]  r''= k*128 + c, rows o'=g*32+j (j<27 real, else 0)
// ---------------------------------------------------------------------------
__global__ __launch_bounds__(256) void prep_k(
    const float* __restrict__ wd, const float* __restrict__ wo,
    ushort* __restrict__ Wt, ushort* __restrict__ Awo) {
  int i = blockIdx.x * 256 + threadIdx.x;
  if (i < 128 * RDIM) {
    int o = i / RDIM, r = i - o * RDIM;
    int g = r / 576, t = r - g * 576;
    int k = t >> 6, cg = t & 63;
    Wt[i] = f2bf(wd[((size_t)o * C_ + g * 64 + cg) * 9 + k]);
  }
  if (i < 64 * RDIM) {
    int o2 = i / RDIM, r = i - o2 * RDIM;
    int k = r >> 7, c = r & 127;
    int g = o2 >> 5, j = o2 & 31;
    float v = (((c >> 6) == g) && (j < 27))
                ? wo[(((size_t)(g * 27 + j)) * 64 + (c & 63)) * 9 + k] : 0.f;
    Awo[i] = f2bf(v);
  }
}

// ---------------------------------------------------------------------------
// Offset conv as MFMA (R3 exact — proven deterministic).
// ---------------------------------------------------------------------------
__global__ __launch_bounds__(256) void offset_mfma_k(
    const float* __restrict__ x, const ushort* __restrict__ Awo,
    const float* __restrict__ b_offset, float* __restrict__ om) {
  __shared__ uint s_val[2][64][20];

  int bid = blockIdx.x;
  int blk = (bid & 7) * 144 + (bid >> 3);
  int wt = blk % 3, bh = blk / 3;
  int ho = bh % HO, b = bh / HO;
  int wo0 = wt * 64;
  int lane = threadIdx.x & 63, wv = threadIdx.x >> 6;

  const float* xb = x + (size_t)b * C_ * HW;
  f32x4 acc[4];
#pragma unroll
  for (int n = 0; n < 4; ++n) acc[n] = (f32x4){0.f, 0.f, 0.f, 0.f};

  const ushort* abase = Awo + (size_t)(wv * 16 + (lane & 15)) * RDIM + (lane >> 4) * 8;

  float gv[8];

  auto patch_gather = [&](int step) {
    int k = step >> 2;
    int dy = k / 3, dx = k - dy * 3;
    int y  = ho - 2 + 2 * dy;
    int xc = wo0 + lane - 2 + 2 * dx;
    bool ok = (y >= 0) & (y < H_) & (xc >= 0) & (xc < W_);
    int c0 = (step & 3) * 32 + wv * 8;
    const float* pl = xb + ((ptrdiff_t)c0 * HW + y * W_ + xc);
#pragma unroll
    for (int j = 0; j < 8; ++j) { gv[j] = ok ? *pl : 0.f; pl += HW; }
  };

  auto patch_finish = [&](int nb) {
    uint res[4];
#pragma unroll
    for (int j = 0; j < 8; ++j) {
      uint bf = (uint)f2bf(gv[j]);
      if (j & 1) res[j >> 1] |= bf << 16; else res[j >> 1] = bf;
    }
    *(int4*)&s_val[nb][lane][wv * 4] = *(int4*)&res[0];
  };

  auto mfma_step = [&](int step, int cb) {
    bf16x8 af = *(const bf16x8*)(abase + step * 32);
#pragma unroll
    for (int n = 0; n < 4; ++n) {
      bf16x8 bfr = *(const bf16x8*)&s_val[cb][n * 16 + (lane & 15)][(lane >> 4) * 4];
      acc[n] = __builtin_amdgcn_mfma_f32_16x16x32_bf16(af, bfr, acc[n], 0, 0, 0);
    }
  };

  patch_gather(0);
  patch_finish(0);
  __syncthreads();
  for (int it = 0; it < NKS - 1; ++it) {
    patch_gather(it + 1);
    mfma_step(it, it & 1);
    patch_finish((it + 1) & 1);
    __syncthreads();
  }
  mfma_step(NKS - 1, (NKS - 1) & 1);

  int col = lane & 15, rgrp = lane >> 4;
#pragma unroll
  for (int n = 0; n < 4; ++n)
#pragma unroll
    for (int ri = 0; ri < 4; ++ri) {
      int o2 = wv * 16 + rgrp * 4 + ri;
      int g = o2 >> 5, j = o2 & 31;
      if (j < 27) {
        int ch = g * 27 + j;
        om[((size_t)(b * OMCH + ch) * HO + ho) * WO + wo0 + n * 16 + col] =
            acc[n][ri] + b_offset[ch];
      }
    }
}

// ---------------------------------------------------------------------------
// Main kernel: 32-px x 128-Cout blocks (grid 2304, 4 waves), canonical
// in-bounds bilinear (corners base,+1,+W,+W+1; clamps folded into weights —
// exact in fp32), paired 8B corner loads, depth-2 gather pipeline with
// triple-buffered val LDS, one barrier per K-step, k-major reduction order.
// ---------------------------------------------------------------------------
__global__ __launch_bounds__(256) void deform_main_k(
    const float* __restrict__ x, const float* __restrict__ om,
    const ushort* __restrict__ Wt, float* __restrict__ out) {
  __shared__ uint  s_addr[18 * 32];        // 2304 B: yb*W+xb (in-bounds base)
  __shared__ uint2 s_wq[18 * 32];          // 4608 B: 4 x f16 folded weights
  __shared__ uint  s_val[3][32][20];       // 7680 B: triple buffer

  int bid = blockIdx.x;
  int blk = (bid & 7) * 288 + (bid >> 3);  // bijective, 2304 % 8 == 0
  int wt = blk % 6, bh = blk / 6;
  int ho = bh % HO, b = bh / HO;
  int wo0 = wt * 32;
  int tid = threadIdx.x;
  int lane = tid & 63, wv = tid >> 6;

  // ---- phase 0: canonical bilinear coefficients, 18 (g,k) x 32 px ----
  for (int e = tid; e < 18 * 32; e += 256) {
    int p = e & 31, gk = e >> 5;
    int g = gk / 9, k = gk - g * 9;
    int wo = wo0 + p;
    const float* omb = om + (size_t)b * OMCH * HW + (size_t)ho * WO + wo;
    float offy = omb[(size_t)(g * 18 + k * 2 + 0) * HW];
    float offx = omb[(size_t)(g * 18 + k * 2 + 1) * HW];
    float z    = omb[(size_t)(36 + g * 9 + k) * HW];
    float msk  = 2.f / (1.f + __expf(-z));
    float py = (float)(ho - 2 + (k / 3) * 2) + offy;
    float px = (float)(wo - 2 + (k % 3) * 2) + offx;
    float y0f = floorf(py), x0f = floorf(px);
    int   y0 = (int)y0f, x0 = (int)x0f;
    float ty = py - y0f, tx = px - x0f;
    float wy0 = (y0 >= 0 && y0 < H_)      ? (1.f - ty) : 0.f;
    float wy1 = (y0 >= -1 && y0 < H_ - 1) ? ty         : 0.f;
    float wx0 = (x0 >= 0 && x0 < W_)      ? (1.f - tx) : 0.f;
    float wx1 = (x0 >= -1 && x0 < W_ - 1) ? tx         : 0.f;
    // canonical in-bounds base; fold clamp into weights (exact):
    int yb  = min(max(y0, 0), H_ - 2);
    int xb_ = min(max(x0, 0), W_ - 2);
    float wAy = (y0 == yb      ? wy0 : 0.f) + (y0 + 1 == yb      ? wy1 : 0.f);
    float wBy = (y0 == yb + 1  ? wy0 : 0.f) + (y0 + 1 == yb + 1  ? wy1 : 0.f);
    float wAx = (x0 == xb_     ? wx0 : 0.f) + (x0 + 1 == xb_     ? wx1 : 0.f);
    float wBx = (x0 == xb_ + 1 ? wx0 : 0.f) + (x0 + 1 == xb_ + 1 ? wx1 : 0.f);
    s_addr[e] = (uint)(yb * W_ + xb_);
    union { __half2 h; uint u; } uA, uB;
    uA.h = __half2{__float2half(wAy * wAx * msk), __float2half(wAy * wBx * msk)};
    uB.h = __half2{__float2half(wBy * wAx * msk), __float2half(wBy * wBx * msk)};
    s_wq[e] = make_uint2(uA.u, uB.u);
  }

  const float* xb = x + (size_t)b * C_ * HW;
  int p = lane & 31;
  int s = (wv << 1) | (lane >> 5);        // 0..7

  f32x4 acc[2][2];
#pragma unroll
  for (int m = 0; m < 2; ++m)
#pragma unroll
    for (int n = 0; n < 2; ++n) acc[m][n] = (f32x4){0.f, 0.f, 0.f, 0.f};

  const ushort* wb0 = Wt + (size_t)(wv * 32 + (lane & 15)) * RDIM + (lane >> 4) * 8;
  const ushort* wb1 = wb0 + (size_t)16 * RDIM;

  // gather sets: G[0..3]=top.x, G[4..7]=top.y, G[8..11]=bot.x, G[12..15]=bot.y
  float GA[16], GB[16];
  float4 wgA, wgB;

  auto val_gather = [&](int step, float (&G)[16], float4& wg) {
    int gg = step >= 18;
    int ks = step - (gg ? 18 : 0);
    int k  = ks >> 1, half = ks & 1;
    int ci = (gg * 9 + k) * 32 + p;
    uint base = s_addr[ci];
    uint2 wq  = s_wq[ci];
    union { __half2 h; uint u; } uA, uB;
    uA.u = wq.x; uB.u = wq.y;
    float2 wA = __half22float2(uA.h);
    float2 wB = __half22float2(uB.h);
    wg = make_float4(wA.x, wA.y, wB.x, wB.y);
    int c0 = gg * 64 + half * 32 + s * 4;
    const float* pl = xb + (size_t)c0 * HW + base;
#pragma unroll
    for (int j = 0; j < 4; ++j) {
      fpair top = *(const fpair*)(pl);
      fpair bot = *(const fpair*)(pl + W_);
      G[j] = top.x; G[4 + j] = top.y; G[8 + j] = bot.x; G[12 + j] = bot.y;
      pl += HW;
    }
  };

  auto val_finish = [&](const float (&G)[16], float4 wg, int nb) {
    uint res[2];
#pragma unroll
    for (int j = 0; j < 4; ++j) {
      float v = wg.x * G[j] + wg.y * G[4 + j] + wg.z * G[8 + j] + wg.w * G[12 + j];
      uint bf = (uint)f2bf(v);
      if (j & 1) res[j >> 1] |= bf << 16; else res[j >> 1] = bf;
    }
    *(uint2*)&s_val[nb][p][s * 2] = make_uint2(res[0], res[1]);
  };

  auto mfma_step = [&](int cb, bf16x8 a0, bf16x8 a1) {
#pragma unroll
    for (int n = 0; n < 2; ++n) {
      bf16x8 bfr = *(const bf16x8*)&s_val[cb][n * 16 + (lane & 15)][(lane >> 4) * 4];
      acc[0][n] = __builtin_amdgcn_mfma_f32_16x16x32_bf16(a0, bfr, acc[0][n], 0, 0, 0);
      acc[1][n] = __builtin_amdgcn_mfma_f32_16x16x32_bf16(a1, bfr, acc[1][n], 0, 0, 0);
    }
  };

  __syncthreads();                 // coeffs ready
  val_gather(0, GA, wgA);
  val_finish(GA, wgA, 0);
  val_gather(1, GB, wgB);
  bf16x8 a0c = *(const bf16x8*)(wb0);
  bf16x8 a1c = *(const bf16x8*)(wb1);
  __syncthreads();                 // buf0 visible

#pragma unroll 6
  for (int it = 0; it < NKS; ++it) {
    // step s uses set (s&1)==0 ? A : B ; gather target for it+2 == set(it&1)
    if (it + 2 < NKS) {
      if ((it & 1) == 0) val_gather(it + 2, GA, wgA);
      else               val_gather(it + 2, GB, wgB);
    }
    bf16x8 a0n = a0c, a1n = a1c;
    if (it + 1 < NKS) {
      a0n = *(const bf16x8*)(wb0 + (it + 1) * 32);
      a1n = *(const bf16x8*)(wb1 + (it + 1) * 32);
    }
    mfma_step(it % 3, a0c, a1c);
    if (it + 1 < NKS) {
      if ((it & 1) == 0) val_finish(GB, wgB, (it + 1) % 3);
      else               val_finish(GA, wgA, (it + 1) % 3);
    }
    __syncthreads();
    a0c = a0n; a1c = a1n;
  }

  // ---- epilogue: C/D layout col=lane&15, row=(lane>>4)*4+reg ----
  int col = lane & 15, rgrp = lane >> 4;
#pragma unroll
  for (int m = 0; m < 2; ++m)
#pragma unroll
    for (int n = 0; n < 2; ++n)
#pragma unroll
      for (int ri = 0; ri < 4; ++ri) {
        int o = wv * 32 + m * 16 + rgrp * 4 + ri;
        out[((size_t)(b * COUT + o) * HO + ho) * WO + wo0 + n * 16 + col] = acc[m][n][ri];
      }
}

// ---------------------------------------------------------------------------
extern "C" void kernel_launch(void* const* d_in, const int* in_sizes, int n_in,
                              void* d_out, int out_size, void* d_ws, size_t ws_size,
                              hipStream_t stream) {
  const float* x        = (const float*)d_in[0];
  const float* w_offset = (const float*)d_in[1];
  const float* b_offset = (const float*)d_in[2];
  const float* w_deform = (const float*)d_in[3];
  float* out = (float*)d_out;

  char* ws = (char*)d_ws;
  float*  om  = (float*)ws;                           // 15,925,248 B
  ushort* Wt  = (ushort*)(ws + 15925248);             //    294,912 B
  ushort* Awo = (ushort*)(ws + 15925248 + 294912);    //    147,456 B

  prep_k<<<576, 256, 0, stream>>>(w_deform, w_offset, Wt, Awo);
  offset_mfma_k<<<1152, 256, 0, stream>>>(x, Awo, b_offset, om);
  deform_main_k<<<2304, 256, 0, stream>>>(x, om, Wt, out);
}